// Round 3
// baseline (2942.740 us; speedup 1.0000x reference)
//
#include <hip/hip_runtime.h>
#include <stdint.h>

#define H 1024
#define NE 16
#define DFF 2730
#define DFFP 2752            // 86*32, zero-padded ffn dim
#define BS 8192
#define KSEL 512             // tokens per expert (expert choice, c=1)

typedef unsigned short u16;
typedef __attribute__((ext_vector_type(8))) short short8;
typedef __attribute__((ext_vector_type(4))) float f32x4;

__device__ __forceinline__ u16 f2b(float f) {
  unsigned u = __float_as_uint(f);
  unsigned r = (u + 0x7fffu + ((u >> 16) & 1u)) >> 16;
  return (u16)r;
}

// ---------------- zero d_out (fp32, poisoned 0xAA before every launch) ----------------
__global__ __launch_bounds__(256) void zero_kernel(f32x4* __restrict__ out) {
  size_t i = ((size_t)blockIdx.x * 256 + threadIdx.x) * 2;
  f32x4 z = {0.f, 0.f, 0.f, 0.f};
  out[i] = z; out[i + 1] = z;
}

// ------- router: fp32 in, fp64 logits+softmax -> S64 [NE][BS], S32 [NE][BS] -------
__global__ __launch_bounds__(256) void router_kernel(
    const float* __restrict__ x, const float* __restrict__ rw,
    const float* __restrict__ rb, double* __restrict__ S64, float* __restrict__ S32) {
  int w = threadIdx.x >> 6, lane = threadIdx.x & 63;
  int t = blockIdx.x * 4 + w;
  __shared__ double part[4][64][17];
  double acc[NE];
#pragma unroll
  for (int e = 0; e < NE; ++e) acc[e] = 0.0;
  const float* xr = x + (size_t)t * H + lane * 16;
  f32x4 xv[4];
#pragma unroll
  for (int q = 0; q < 4; ++q) xv[q] = *(const f32x4*)(xr + q * 4);
#pragma unroll
  for (int hh = 0; hh < 16; ++hh) {
    double xf = (double)xv[hh >> 2][hh & 3];
    const float* rwr = rw + (size_t)(lane * 16 + hh) * NE;
    f32x4 wv0 = *(const f32x4*)rwr;
    f32x4 wv1 = *(const f32x4*)(rwr + 4);
    f32x4 wv2 = *(const f32x4*)(rwr + 8);
    f32x4 wv3 = *(const f32x4*)(rwr + 12);
#pragma unroll
    for (int e = 0; e < 4; ++e) acc[e]      += xf * (double)wv0[e];
#pragma unroll
    for (int e = 0; e < 4; ++e) acc[4 + e]  += xf * (double)wv1[e];
#pragma unroll
    for (int e = 0; e < 4; ++e) acc[8 + e]  += xf * (double)wv2[e];
#pragma unroll
    for (int e = 0; e < 4; ++e) acc[12 + e] += xf * (double)wv3[e];
  }
#pragma unroll
  for (int e = 0; e < NE; ++e) part[w][lane][e] = acc[e];
  __syncthreads();
  if (lane < NE) {
    double s = (double)rb[lane];
#pragma unroll 8
    for (int r = 0; r < 64; ++r) s += part[w][r][lane];
    double m = s;
    for (int o = 8; o > 0; o >>= 1) m = fmax(m, __shfl_xor(m, o, 16));
    double ex = exp(s - m);
    double sum = ex;
    for (int o = 8; o > 0; o >>= 1) sum += __shfl_xor(sum, o, 16);
    double Sv = ex / sum;
    S64[(size_t)lane * BS + t] = Sv;
    S32[(size_t)lane * BS + t] = (float)Sv;
  }
}

// ---------------- exact top-k (k=512) per expert, fp64 tie-refinement ----------------
__global__ __launch_bounds__(256) void topk_kernel(
    const float* __restrict__ S32, const double* __restrict__ S64,
    int* __restrict__ sel, float* __restrict__ gates) {
  int e = blockIdx.x, tid = threadIdx.x;
  __shared__ float sv[BS];
  __shared__ int red[4];
  __shared__ int cnt_s, gt_s, tie_cnt;
  __shared__ int tie_idx[256];
  const float* row = S32 + (size_t)e * BS;
  for (int i = tid; i < BS; i += 256) sv[i] = row[i];
  if (tid == 0) tie_cnt = 0;
  __syncthreads();
  // binary search on the uint bit pattern: max thr with count(bits >= thr) >= KSEL
  unsigned thr = 0;
  for (int bit = 31; bit >= 0; --bit) {
    unsigned cand = thr | (1u << bit);
    int c = 0;
    for (int i = tid; i < BS; i += 256) c += (__float_as_uint(sv[i]) >= cand) ? 1 : 0;
#pragma unroll
    for (int o = 32; o > 0; o >>= 1) c += __shfl_down(c, o);
    if ((tid & 63) == 0) red[tid >> 6] = c;
    __syncthreads();
    if (tid == 0) cnt_s = red[0] + red[1] + red[2] + red[3];
    __syncthreads();
    if (cnt_s >= KSEL) thr = cand;
    __syncthreads();
  }
  // count strictly greater
  {
    int c = 0;
    for (int i = tid; i < BS; i += 256) c += (__float_as_uint(sv[i]) > thr) ? 1 : 0;
#pragma unroll
    for (int o = 32; o > 0; o >>= 1) c += __shfl_down(c, o);
    if ((tid & 63) == 0) red[tid >> 6] = c;
    __syncthreads();
    if (tid == 0) gt_s = red[0] + red[1] + red[2] + red[3];
    __syncthreads();
  }
  int gt = gt_s;
  // wave 0: compact strictly-greater in ascending index order -> slots [0, gt)
  if (tid < 64) {
    int lane = tid, pos = 0;
    for (int c = 0; c < BS / 64; ++c) {
      int i = c * 64 + lane;
      bool p = __float_as_uint(sv[i]) > thr;
      unsigned long long b = __ballot(p);
      int rank = __popcll(b & ((1ull << lane) - 1ull));
      if (p) { sel[e * KSEL + pos + rank] = i; gates[e * KSEL + pos + rank] = sv[i]; }
      pos += __popcll(b);
    }
  }
  // collect ties (bits == thr)
  for (int i = tid; i < BS; i += 256) {
    if (__float_as_uint(sv[i]) == thr) {
      int p = atomicAdd(&tie_cnt, 1);
      if (p < 256) tie_idx[p] = i;
    }
  }
  __syncthreads();
  int T = tie_cnt < 256 ? tie_cnt : 256;
  int R = KSEL - gt;               // 1 <= R <= T
  // rank ties by (S64 desc, index asc); first R win slots [gt, KSEL)
  if (tid < T) {
    int i = tie_idx[tid];
    double vi = S64[(size_t)e * BS + i];
    int rank = 0;
    for (int j = 0; j < T; ++j) {
      if (j == tid) continue;
      int kdx = tie_idx[j];
      double vj = S64[(size_t)e * BS + kdx];
      rank += (vj > vi || (vj == vi && kdx < i)) ? 1 : 0;
    }
    if (rank < R) {
      sel[e * KSEL + gt + rank] = i;
      gates[e * KSEL + gt + rank] = sv[i];
    }
  }
}

// ------- up GEMM: hid[z][m][n] = silu(bf16(x[sel]) @ bf16(up_w[e]) + up_b[e]) -------
__global__ __launch_bounds__(256) void up_gemm_kernel(
    const float* __restrict__ x, const int* __restrict__ sel,
    const float* __restrict__ up_w, const float* __restrict__ up_b,
    u16* __restrict__ hid, int e_base) {
  int nt = blockIdx.x;            // 0..21
  int mt = blockIdx.y;            // 0..3
  int z = blockIdx.z;
  int e = e_base + z;
  int tid = threadIdx.x, lane = tid & 63, w = tid >> 6;
  int wm = (w >> 1) * 64, wn = (w & 1) * 64;
  int n0 = nt * 128, m0 = mt * 128;
  __shared__ u16 As[128][32];
  __shared__ u16 Bs[128][32];
  __shared__ int sel_s[128];
  if (tid < 128) sel_s[tid] = sel[e * KSEL + m0 + tid];
  f32x4 zero = {0.f, 0.f, 0.f, 0.f};
  f32x4 acc[4][4];
#pragma unroll
  for (int i = 0; i < 4; ++i)
#pragma unroll
    for (int j = 0; j < 4; ++j) acc[i][j] = zero;
  const float* Bbase = up_w + (size_t)e * H * DFF;
  int bn = tid & 127, bh = tid >> 7;          // bh in 0..1 -> k-halves of 16
  bool bvalid = (n0 + bn) < DFF;
  const float* bcol = Bbase + (bvalid ? (n0 + bn) : 0);
  int arow = tid >> 1, ahalf = tid & 1;       // 128 rows x 2 sixteen-float halves
  __syncthreads();
  for (int k0 = 0; k0 < H; k0 += 32) {
    const float* ap = x + (size_t)sel_s[arow] * H + k0 + ahalf * 16;
    f32x4 a0 = *(const f32x4*)ap;
    f32x4 a1 = *(const f32x4*)(ap + 4);
    f32x4 a2 = *(const f32x4*)(ap + 8);
    f32x4 a3 = *(const f32x4*)(ap + 12);
    short8 pa0, pa1;
#pragma unroll
    for (int q = 0; q < 4; ++q) { pa0[q] = (short)f2b(a0[q]); pa0[4 + q] = (short)f2b(a1[q]); }
#pragma unroll
    for (int q = 0; q < 4; ++q) { pa1[q] = (short)f2b(a2[q]); pa1[4 + q] = (short)f2b(a3[q]); }
    short8 qb0, qb1;
#pragma unroll
    for (int kk = 0; kk < 8; ++kk)
      qb0[kk] = (short)f2b(bcol[(size_t)(k0 + bh * 16 + kk) * DFF]);
#pragma unroll
    for (int kk = 0; kk < 8; ++kk)
      qb1[kk] = (short)f2b(bcol[(size_t)(k0 + bh * 16 + 8 + kk) * DFF]);
    if (!bvalid) {
      short8 z8 = {0, 0, 0, 0, 0, 0, 0, 0};
      qb0 = z8; qb1 = z8;
    }
    __syncthreads();
    *(short8*)&As[arow][ahalf * 16] = pa0;
    *(short8*)&As[arow][ahalf * 16 + 8] = pa1;
    *(short8*)&Bs[bn][bh * 16] = qb0;
    *(short8*)&Bs[bn][bh * 16 + 8] = qb1;
    __syncthreads();
    int lm = lane & 15, lk = (lane >> 4) * 8;
    short8 af[4], bfr[4];
#pragma unroll
    for (int i = 0; i < 4; ++i) af[i] = *(short8*)&As[wm + i * 16 + lm][lk];
#pragma unroll
    for (int j = 0; j < 4; ++j) bfr[j] = *(short8*)&Bs[wn + j * 16 + lm][lk];
#pragma unroll
    for (int i = 0; i < 4; ++i)
#pragma unroll
      for (int j = 0; j < 4; ++j)
        acc[i][j] = __builtin_amdgcn_mfma_f32_16x16x32_bf16(af[i], bfr[j], acc[i][j], 0, 0, 0);
  }
  int lm = lane & 15, q = lane >> 4;
#pragma unroll
  for (int i = 0; i < 4; ++i) {
#pragma unroll
    for (int j = 0; j < 4; ++j) {
      int col = n0 + wn + j * 16 + lm;
      if (col >= DFFP) continue;
      float bias = (col < DFF) ? up_b[(size_t)e * DFF + col] : 0.f;
#pragma unroll
      for (int r = 0; r < 4; ++r) {
        int rowl = m0 + wm + i * 16 + q * 4 + r;
        float v = acc[i][j][r] + bias;
        v = v / (1.f + __expf(-v));           // silu
        hid[((size_t)z * KSEL + rowl) * DFFP + col] = f2b(v);
      }
    }
  }
}

// ------- down GEMM (group-merged M) + gated fp32 atomicAdd scatter into out -------
__global__ __launch_bounds__(256) void down_gemm_kernel(
    const u16* __restrict__ hid, const float* __restrict__ dwg,
    const float* __restrict__ dbg, const int* __restrict__ selp,
    const float* __restrict__ gatesp, float* __restrict__ out) {
  int nt = blockIdx.x;            // 0..7
  int mt = blockIdx.y;
  int tid = threadIdx.x, lane = tid & 63, w = tid >> 6;
  int wm = (w >> 1) * 64, wn = (w & 1) * 64;
  int n0 = nt * 128, m0 = mt * 128;
  __shared__ u16 As[128][32];
  __shared__ u16 Bs[128][32];
  __shared__ int sel_s[128];
  __shared__ float gate_s[128];
  if (tid < 128) {
    sel_s[tid] = selp[m0 + tid];
    gate_s[tid] = gatesp[m0 + tid];
  }
  f32x4 zero = {0.f, 0.f, 0.f, 0.f};
  f32x4 acc[4][4];
#pragma unroll
  for (int i = 0; i < 4; ++i)
#pragma unroll
    for (int j = 0; j < 4; ++j) acc[i][j] = zero;
  int bn = tid & 127, bh = tid >> 7;
  const float* bcol = dwg + n0 + bn;
  int arow0 = tid >> 2, akv = tid & 3;
  __syncthreads();
  for (int k0 = 0; k0 < DFFP; k0 += 32) {
    short8 av0 = *(const short8*)(hid + (size_t)(m0 + arow0) * DFFP + k0 + akv * 8);
    short8 av1 = *(const short8*)(hid + (size_t)(m0 + arow0 + 64) * DFFP + k0 + akv * 8);
    short8 qb0, qb1;
#pragma unroll
    for (int kk = 0; kk < 8; ++kk) {
      int k = k0 + bh * 16 + kk;
      int kc = k < DFF ? k : 0;
      float t = bcol[(size_t)kc * H];
      qb0[kk] = (k < DFF) ? (short)f2b(t) : (short)0;
    }
#pragma unroll
    for (int kk = 0; kk < 8; ++kk) {
      int k = k0 + bh * 16 + 8 + kk;
      int kc = k < DFF ? k : 0;
      float t = bcol[(size_t)kc * H];
      qb1[kk] = (k < DFF) ? (short)f2b(t) : (short)0;
    }
    __syncthreads();
    *(short8*)&As[arow0][akv * 8] = av0;
    *(short8*)&As[arow0 + 64][akv * 8] = av1;
    *(short8*)&Bs[bn][bh * 16] = qb0;
    *(short8*)&Bs[bn][bh * 16 + 8] = qb1;
    __syncthreads();
    int lm = lane & 15, lk = (lane >> 4) * 8;
    short8 af[4], bfr[4];
#pragma unroll
    for (int i = 0; i < 4; ++i) af[i] = *(short8*)&As[wm + i * 16 + lm][lk];
#pragma unroll
    for (int j = 0; j < 4; ++j) bfr[j] = *(short8*)&Bs[wn + j * 16 + lm][lk];
#pragma unroll
    for (int i = 0; i < 4; ++i)
#pragma unroll
      for (int j = 0; j < 4; ++j)
        acc[i][j] = __builtin_amdgcn_mfma_f32_16x16x32_bf16(af[i], bfr[j], acc[i][j], 0, 0, 0);
  }
  int lm = lane & 15, q = lane >> 4;
#pragma unroll
  for (int i = 0; i < 4; ++i) {
#pragma unroll
    for (int j = 0; j < 4; ++j) {
      int col = n0 + wn + j * 16 + lm;
      float bias = dbg[col];
#pragma unroll
      for (int r = 0; r < 4; ++r) {
        int rowl = wm + i * 16 + q * 4 + r;
        float v = (acc[i][j][r] + bias) * gate_s[rowl];
        atomicAdd(&out[(size_t)sel_s[rowl] * H + col], v);
      }
    }
  }
}

extern "C" void kernel_launch(void* const* d_in, const int* in_sizes, int n_in,
                              void* d_out, int out_size, void* d_ws, size_t ws_size,
                              hipStream_t stream) {
  const float* x      = (const float*)d_in[0];
  const float* rw     = (const float*)d_in[1];
  const float* rb     = (const float*)d_in[2];
  const float* up_w   = (const float*)d_in[3];
  const float* up_b   = (const float*)d_in[4];
  const float* down_w = (const float*)d_in[5];
  const float* down_b = (const float*)d_in[6];
  char* ws = (char*)d_ws;
  double* S64  = (double*)ws;                  // 1,048,576 B
  float*  S32  = (float*)(ws + 1048576);       //   524,288 B
  int*    sel  = (int*)(ws + 1572864);         //    32,768 B
  float*  gates= (float*)(ws + 1605632);       //    32,768 B
  u16*    hid  = (u16*)(ws + 1638400);         // epc * 512 * DFFP * 2 bytes

  const size_t per_e = (size_t)KSEL * DFFP * 2;   // 2,818,048 B per expert
  size_t avail = ws_size > 1638400 ? ws_size - 1638400 : 0;
  int epc = (avail >= 16 * per_e) ? 16 : (avail >= 4 * per_e ? 4 : 1);

  float* outf = (float*)d_out;
  zero_kernel<<<BS * H / 8 / 256, 256, 0, stream>>>((f32x4*)d_out);
  router_kernel<<<BS / 4, 256, 0, stream>>>(x, rw, rb, S64, S32);
  topk_kernel<<<NE, 256, 0, stream>>>(S32, S64, sel, gates);

  if (epc == 16) {
    up_gemm_kernel<<<dim3(22, 4, 16), 256, 0, stream>>>(x, sel, up_w, up_b, hid, 0);
    for (int g = 0; g < 4; ++g)
      down_gemm_kernel<<<dim3(8, 16), 256, 0, stream>>>(
          hid + (size_t)g * 2048 * DFFP, down_w + (size_t)g * DFF * H,
          down_b + g * H, sel + g * 2048, gates + g * 2048, outf);
  } else if (epc == 4) {
    for (int g = 0; g < 4; ++g) {
      up_gemm_kernel<<<dim3(22, 4, 4), 256, 0, stream>>>(x, sel, up_w, up_b, hid, g * 4);
      down_gemm_kernel<<<dim3(8, 16), 256, 0, stream>>>(
          hid, down_w + (size_t)g * DFF * H,
          down_b + g * H, sel + g * 2048, gates + g * 2048, outf);
    }
  } else {
    for (int e = 0; e < 16; ++e) {
      up_gemm_kernel<<<dim3(22, 4, 1), 256, 0, stream>>>(x, sel, up_w, up_b, hid, e);
      down_gemm_kernel<<<dim3(8, 4), 256, 0, stream>>>(
          hid, down_w + (size_t)(e >> 2) * DFF * H,
          down_b + (e >> 2) * H, sel + e * KSEL, gates + e * KSEL, outf);
    }
  }
}

// Round 4
// 705.649 us; speedup vs baseline: 4.1703x; 4.1703x over previous
//
#include <hip/hip_runtime.h>
#include <stdint.h>

#define H 1024
#define NE 16
#define DFF 2730
#define DFFP 2752            // 86*32, zero-padded ffn dim (hid cols / down K)
#define DFFT 2816            // 22*128, padded row count for up_w^T (up N tiles)
#define BS 8192
#define KSEL 512             // tokens per expert (expert choice, c=1)
#define LDSP 40              // LDS tile row pitch in u16 (80B = 20 banks, conflict-free)

typedef unsigned short u16;
typedef __attribute__((ext_vector_type(8))) short short8;
typedef __attribute__((ext_vector_type(4))) float f32x4;

__device__ __forceinline__ u16 f2b(float f) {
  unsigned u = __float_as_uint(f);
  unsigned r = (u + 0x7fffu + ((u >> 16) & 1u)) >> 16;
  return (u16)r;
}

// ---------------- zero d_out (fp32, poisoned 0xAA before every launch) ----------------
__global__ __launch_bounds__(256) void zero_kernel(f32x4* __restrict__ out) {
  size_t i = ((size_t)blockIdx.x * 256 + threadIdx.x) * 2;
  f32x4 z = {0.f, 0.f, 0.f, 0.f};
  out[i] = z; out[i + 1] = z;
}

// ------- transpose+convert: src fp32 [Ks][Ns] -> dst bf16 [Nd rows][Kd cols] -------
// zero-pads rows n>=Ns and cols k>=Ks. blockIdx.z strides by src_z / dst_z elements.
__global__ __launch_bounds__(256) void transcvt_kernel(
    const float* __restrict__ src, u16* __restrict__ dst,
    int Ks, int Ns, int Kd, long src_z, long dst_z) {
  src += (size_t)blockIdx.z * src_z;
  dst += (size_t)blockIdx.z * dst_z;
  __shared__ float t[32][33];
  int k0 = blockIdx.x * 32, n0 = blockIdx.y * 32;
  int r = threadIdx.x >> 3, c4 = (threadIdx.x & 7) * 4;
  int k = k0 + r;
#pragma unroll
  for (int j = 0; j < 4; ++j) {
    int n = n0 + c4 + j;
    t[r][c4 + j] = (k < Ks && n < Ns) ? src[(size_t)k * Ns + n] : 0.f;
  }
  __syncthreads();
  u16 o[4];
#pragma unroll
  for (int j = 0; j < 4; ++j) o[j] = f2b(t[c4 + j][r]);
  *(uint2*)&dst[(size_t)(n0 + r) * Kd + k0 + c4] = *(uint2*)o;
}

// ------- router: fp32 in, fp64 logits+softmax -> S64 [NE][BS], S32 [NE][BS] -------
__global__ __launch_bounds__(256) void router_kernel(
    const float* __restrict__ x, const float* __restrict__ rw,
    const float* __restrict__ rb, double* __restrict__ S64, float* __restrict__ S32) {
  int w = threadIdx.x >> 6, lane = threadIdx.x & 63;
  int t = blockIdx.x * 4 + w;
  __shared__ double part[4][64][17];
  double acc[NE];
#pragma unroll
  for (int e = 0; e < NE; ++e) acc[e] = 0.0;
  const float* xr = x + (size_t)t * H + lane * 16;
  f32x4 xv[4];
#pragma unroll
  for (int q = 0; q < 4; ++q) xv[q] = *(const f32x4*)(xr + q * 4);
#pragma unroll
  for (int hh = 0; hh < 16; ++hh) {
    double xf = (double)xv[hh >> 2][hh & 3];
    const float* rwr = rw + (size_t)(lane * 16 + hh) * NE;
    f32x4 wv0 = *(const f32x4*)rwr;
    f32x4 wv1 = *(const f32x4*)(rwr + 4);
    f32x4 wv2 = *(const f32x4*)(rwr + 8);
    f32x4 wv3 = *(const f32x4*)(rwr + 12);
#pragma unroll
    for (int e = 0; e < 4; ++e) acc[e]      += xf * (double)wv0[e];
#pragma unroll
    for (int e = 0; e < 4; ++e) acc[4 + e]  += xf * (double)wv1[e];
#pragma unroll
    for (int e = 0; e < 4; ++e) acc[8 + e]  += xf * (double)wv2[e];
#pragma unroll
    for (int e = 0; e < 4; ++e) acc[12 + e] += xf * (double)wv3[e];
  }
#pragma unroll
  for (int e = 0; e < NE; ++e) part[w][lane][e] = acc[e];
  __syncthreads();
  if (lane < NE) {
    double s = (double)rb[lane];
#pragma unroll 8
    for (int r = 0; r < 64; ++r) s += part[w][r][lane];
    double m = s;
    for (int o = 8; o > 0; o >>= 1) m = fmax(m, __shfl_xor(m, o, 16));
    double ex = exp(s - m);
    double sum = ex;
    for (int o = 8; o > 0; o >>= 1) sum += __shfl_xor(sum, o, 16);
    double Sv = ex / sum;
    S64[(size_t)lane * BS + t] = Sv;
    S32[(size_t)lane * BS + t] = (float)Sv;
  }
}

// ---------------- exact top-k (k=512) per expert, fp64 tie-refinement ----------------
__global__ __launch_bounds__(256) void topk_kernel(
    const float* __restrict__ S32, const double* __restrict__ S64,
    int* __restrict__ sel, float* __restrict__ gates) {
  int e = blockIdx.x, tid = threadIdx.x;
  __shared__ float sv[BS];
  __shared__ int red[4];
  __shared__ int cnt_s, gt_s, tie_cnt;
  __shared__ int tie_idx[256];
  const float* row = S32 + (size_t)e * BS;
  for (int i = tid; i < BS; i += 256) sv[i] = row[i];
  if (tid == 0) tie_cnt = 0;
  __syncthreads();
  unsigned thr = 0;
  for (int bit = 31; bit >= 0; --bit) {
    unsigned cand = thr | (1u << bit);
    int c = 0;
    for (int i = tid; i < BS; i += 256) c += (__float_as_uint(sv[i]) >= cand) ? 1 : 0;
#pragma unroll
    for (int o = 32; o > 0; o >>= 1) c += __shfl_down(c, o);
    if ((tid & 63) == 0) red[tid >> 6] = c;
    __syncthreads();
    if (tid == 0) cnt_s = red[0] + red[1] + red[2] + red[3];
    __syncthreads();
    if (cnt_s >= KSEL) thr = cand;
    __syncthreads();
  }
  {
    int c = 0;
    for (int i = tid; i < BS; i += 256) c += (__float_as_uint(sv[i]) > thr) ? 1 : 0;
#pragma unroll
    for (int o = 32; o > 0; o >>= 1) c += __shfl_down(c, o);
    if ((tid & 63) == 0) red[tid >> 6] = c;
    __syncthreads();
    if (tid == 0) gt_s = red[0] + red[1] + red[2] + red[3];
    __syncthreads();
  }
  int gt = gt_s;
  if (tid < 64) {
    int lane = tid, pos = 0;
    for (int c = 0; c < BS / 64; ++c) {
      int i = c * 64 + lane;
      bool p = __float_as_uint(sv[i]) > thr;
      unsigned long long b = __ballot(p);
      int rank = __popcll(b & ((1ull << lane) - 1ull));
      if (p) { sel[e * KSEL + pos + rank] = i; gates[e * KSEL + pos + rank] = sv[i]; }
      pos += __popcll(b);
    }
  }
  for (int i = tid; i < BS; i += 256) {
    if (__float_as_uint(sv[i]) == thr) {
      int p = atomicAdd(&tie_cnt, 1);
      if (p < 256) tie_idx[p] = i;
    }
  }
  __syncthreads();
  int T = tie_cnt < 256 ? tie_cnt : 256;
  int R = KSEL - gt;
  if (tid < T) {
    int i = tie_idx[tid];
    double vi = S64[(size_t)e * BS + i];
    int rank = 0;
    for (int j = 0; j < T; ++j) {
      if (j == tid) continue;
      int kdx = tie_idx[j];
      double vj = S64[(size_t)e * BS + kdx];
      rank += (vj > vi || (vj == vi && kdx < i)) ? 1 : 0;
    }
    if (rank < R) {
      sel[e * KSEL + gt + rank] = i;
      gates[e * KSEL + gt + rank] = sv[i];
    }
  }
}

// ------- up GEMM: hid[z][m][n] = silu(bf16(x[sel]) @ upT[z]^T + up_b[e]) -------
// upT: bf16 [DFFT rows(n)][H cols(k)] per expert; z = local expert; e = e_base + z
__global__ __launch_bounds__(256) void up_gemm_kernel(
    const float* __restrict__ x, const int* __restrict__ sel,
    const u16* __restrict__ upT, const float* __restrict__ up_b,
    u16* __restrict__ hid, int e_base) {
  int nt = blockIdx.x;            // 0..21
  int mt = blockIdx.y;            // 0..3
  int z = blockIdx.z;
  int e = e_base + z;
  const u16* upTz = upT + (size_t)z * DFFT * H;
  u16* hidz = hid + (size_t)z * KSEL * DFFP;
  int tid = threadIdx.x, lane = tid & 63, w = tid >> 6;
  int wm = (w >> 1) * 64, wn = (w & 1) * 64;
  int n0 = nt * 128, m0 = mt * 128;
  __shared__ u16 As[128][LDSP];
  __shared__ u16 Bs[128][LDSP];
  __shared__ int sel_s[128];
  if (tid < 128) sel_s[tid] = sel[e * KSEL + m0 + tid];
  f32x4 zero = {0.f, 0.f, 0.f, 0.f};
  f32x4 acc[4][4];
#pragma unroll
  for (int i = 0; i < 4; ++i)
#pragma unroll
    for (int j = 0; j < 4; ++j) acc[i][j] = zero;
  int bn = tid & 127, bq = tid >> 7;          // bq: k-half (0/1)
  const u16* brow = upTz + (size_t)(n0 + bn) * H + bq * 16;
  int arow = tid >> 1, ahalf = tid & 1;       // 128 rows x 2 sixteen-float halves
  __syncthreads();
  const float* xrow = x + (size_t)sel_s[arow] * H + ahalf * 16;
  for (int k0 = 0; k0 < H; k0 += 32) {
    const float* ap = xrow + k0;
    f32x4 a0 = *(const f32x4*)ap;
    f32x4 a1 = *(const f32x4*)(ap + 4);
    f32x4 a2 = *(const f32x4*)(ap + 8);
    f32x4 a3 = *(const f32x4*)(ap + 12);
    short8 pa0, pa1;
#pragma unroll
    for (int q = 0; q < 4; ++q) { pa0[q] = (short)f2b(a0[q]); pa0[4 + q] = (short)f2b(a1[q]); }
#pragma unroll
    for (int q = 0; q < 4; ++q) { pa1[q] = (short)f2b(a2[q]); pa1[4 + q] = (short)f2b(a3[q]); }
    short8 qb0 = *(const short8*)(brow + k0);
    short8 qb1 = *(const short8*)(brow + k0 + 8);
    __syncthreads();
    *(short8*)&As[arow][ahalf * 16] = pa0;
    *(short8*)&As[arow][ahalf * 16 + 8] = pa1;
    *(short8*)&Bs[bn][bq * 16] = qb0;
    *(short8*)&Bs[bn][bq * 16 + 8] = qb1;
    __syncthreads();
    int lm = lane & 15, lk = (lane >> 4) * 8;
    short8 af[4], bfr[4];
#pragma unroll
    for (int i = 0; i < 4; ++i) af[i] = *(short8*)&As[wm + i * 16 + lm][lk];
#pragma unroll
    for (int j = 0; j < 4; ++j) bfr[j] = *(short8*)&Bs[wn + j * 16 + lm][lk];
#pragma unroll
    for (int i = 0; i < 4; ++i)
#pragma unroll
      for (int j = 0; j < 4; ++j)
        acc[i][j] = __builtin_amdgcn_mfma_f32_16x16x32_bf16(af[i], bfr[j], acc[i][j], 0, 0, 0);
  }
  int lm = lane & 15, q = lane >> 4;
#pragma unroll
  for (int i = 0; i < 4; ++i) {
#pragma unroll
    for (int j = 0; j < 4; ++j) {
      int col = n0 + wn + j * 16 + lm;
      if (col >= DFFP) continue;
      float bias = (col < DFF) ? up_b[(size_t)e * DFF + col] : 0.f;
#pragma unroll
      for (int r = 0; r < 4; ++r) {
        int rowl = m0 + wm + i * 16 + q * 4 + r;
        float v = acc[i][j][r] + bias;
        v = v / (1.f + __expf(-v));           // silu
        hidz[(size_t)rowl * DFFP + col] = f2b(v);
      }
    }
  }
}

// ------- down GEMM (z = group) + gated fp32 atomicAdd scatter into out -------
// dwT: bf16 [H rows(n)][DFFP cols(k)] per group (k zero-padded)
__global__ __launch_bounds__(256) void down_gemm_kernel(
    const u16* __restrict__ hid, const u16* __restrict__ dwT,
    const float* __restrict__ db, const int* __restrict__ selp,
    const float* __restrict__ gatesp, float* __restrict__ out) {
  int nt = blockIdx.x;            // 0..7
  int mt = blockIdx.y;
  int z = blockIdx.z;             // group (extent 4 on full path, else 1)
  const u16* hidz = hid + (size_t)z * 2048 * DFFP;
  const u16* dwTz = dwT + (size_t)z * H * DFFP;
  const float* dbz = db + (size_t)z * H;
  const int* selz = selp + z * 2048;
  const float* gatesz = gatesp + z * 2048;
  int tid = threadIdx.x, lane = tid & 63, w = tid >> 6;
  int wm = (w >> 1) * 64, wn = (w & 1) * 64;
  int n0 = nt * 128, m0 = mt * 128;
  __shared__ u16 As[128][LDSP];
  __shared__ u16 Bs[128][LDSP];
  __shared__ int sel_s[128];
  __shared__ float gate_s[128];
  if (tid < 128) {
    sel_s[tid] = selz[m0 + tid];
    gate_s[tid] = gatesz[m0 + tid];
  }
  f32x4 zero = {0.f, 0.f, 0.f, 0.f};
  f32x4 acc[4][4];
#pragma unroll
  for (int i = 0; i < 4; ++i)
#pragma unroll
    for (int j = 0; j < 4; ++j) acc[i][j] = zero;
  int bn = tid & 127, bq = tid >> 7;
  const u16* brow = dwTz + (size_t)(n0 + bn) * DFFP + bq * 16;
  int arow0 = tid >> 2, akv = tid & 3;
  __syncthreads();
  for (int k0 = 0; k0 < DFFP; k0 += 32) {
    short8 av0 = *(const short8*)(hidz + (size_t)(m0 + arow0) * DFFP + k0 + akv * 8);
    short8 av1 = *(const short8*)(hidz + (size_t)(m0 + arow0 + 64) * DFFP + k0 + akv * 8);
    short8 qb0 = *(const short8*)(brow + k0);
    short8 qb1 = *(const short8*)(brow + k0 + 8);
    __syncthreads();
    *(short8*)&As[arow0][akv * 8] = av0;
    *(short8*)&As[arow0 + 64][akv * 8] = av1;
    *(short8*)&Bs[bn][bq * 16] = qb0;
    *(short8*)&Bs[bn][bq * 16 + 8] = qb1;
    __syncthreads();
    int lm = lane & 15, lk = (lane >> 4) * 8;
    short8 af[4], bfr[4];
#pragma unroll
    for (int i = 0; i < 4; ++i) af[i] = *(short8*)&As[wm + i * 16 + lm][lk];
#pragma unroll
    for (int j = 0; j < 4; ++j) bfr[j] = *(short8*)&Bs[wn + j * 16 + lm][lk];
#pragma unroll
    for (int i = 0; i < 4; ++i)
#pragma unroll
      for (int j = 0; j < 4; ++j)
        acc[i][j] = __builtin_amdgcn_mfma_f32_16x16x32_bf16(af[i], bfr[j], acc[i][j], 0, 0, 0);
  }
  int lm = lane & 15, q = lane >> 4;
#pragma unroll
  for (int i = 0; i < 4; ++i) {
#pragma unroll
    for (int j = 0; j < 4; ++j) {
      int col = n0 + wn + j * 16 + lm;
      float bias = dbz[col];
#pragma unroll
      for (int r = 0; r < 4; ++r) {
        int rowl = wm + i * 16 + q * 4 + r;
        float v = (acc[i][j][r] + bias) * gate_s[rowl];
        atomicAdd(&out[(size_t)sel_s[rowl] * H + col], v);
      }
    }
  }
}

extern "C" void kernel_launch(void* const* d_in, const int* in_sizes, int n_in,
                              void* d_out, int out_size, void* d_ws, size_t ws_size,
                              hipStream_t stream) {
  const float* x      = (const float*)d_in[0];
  const float* rw     = (const float*)d_in[1];
  const float* rb     = (const float*)d_in[2];
  const float* up_w   = (const float*)d_in[3];
  const float* up_b   = (const float*)d_in[4];
  const float* down_w = (const float*)d_in[5];
  const float* down_b = (const float*)d_in[6];
  char* ws = (char*)d_ws;
  double* S64  = (double*)ws;                  // 1,048,576 B
  float*  S32  = (float*)(ws + 1048576);       //   524,288 B
  int*    sel  = (int*)(ws + 1572864);         //    32,768 B
  float*  gates= (float*)(ws + 1605632);       //    32,768 B
  const size_t base = 1638400;

  const size_t upT_e  = (size_t)DFFT * H * 2;     // 5,767,168 B per expert
  const size_t dwT_g  = (size_t)H * DFFP * 2;     // 5,636,096 B per group
  const size_t hid_e  = (size_t)KSEL * DFFP * 2;  // 2,818,048 B per expert

  size_t need16 = base + 16 * upT_e + 4 * dwT_g + 16 * hid_e;  // ~163 MB
  size_t need4  = base + 4 * upT_e + 1 * dwT_g + 4 * hid_e;    // ~41.6 MB
  int cs = (ws_size >= need16) ? 16 : (ws_size >= need4 ? 4 : 1);

  float* outf = (float*)d_out;
  zero_kernel<<<BS * H / 8 / 256, 256, 0, stream>>>((f32x4*)d_out);
  router_kernel<<<BS / 4, 256, 0, stream>>>(x, rw, rb, S64, S32);
  topk_kernel<<<NE, 256, 0, stream>>>(S32, S64, sel, gates);

  if (cs == 16) {
    u16* upT = (u16*)(ws + base);
    u16* dwT = (u16*)(ws + base + 16 * upT_e);
    u16* hid = (u16*)(ws + base + 16 * upT_e + 4 * dwT_g);
    transcvt_kernel<<<dim3(H / 32, DFFT / 32, 16), 256, 0, stream>>>(
        up_w, upT, H, DFF, H, (long)H * DFF, (long)DFFT * H);
    transcvt_kernel<<<dim3(DFFP / 32, H / 32, 4), 256, 0, stream>>>(
        down_w, dwT, DFF, H, DFFP, (long)DFF * H, (long)H * DFFP);
    up_gemm_kernel<<<dim3(22, 4, 16), 256, 0, stream>>>(x, sel, upT, up_b, hid, 0);
    down_gemm_kernel<<<dim3(8, 16, 4), 256, 0, stream>>>(hid, dwT, down_b, sel, gates, outf);
  } else if (cs == 4) {
    u16* upT = (u16*)(ws + base);
    u16* dwT = (u16*)(ws + base + 4 * upT_e);
    u16* hid = (u16*)(ws + base + 4 * upT_e + dwT_g);
    for (int g = 0; g < 4; ++g) {
      transcvt_kernel<<<dim3(H / 32, DFFT / 32, 4), 256, 0, stream>>>(
          up_w + (size_t)g * 4 * H * DFF, upT, H, DFF, H, (long)H * DFF, (long)DFFT * H);
      transcvt_kernel<<<dim3(DFFP / 32, H / 32, 1), 256, 0, stream>>>(
          down_w + (size_t)g * DFF * H, dwT, DFF, H, DFFP, 0, 0);
      up_gemm_kernel<<<dim3(22, 4, 4), 256, 0, stream>>>(x, sel, upT, up_b, hid, g * 4);
      down_gemm_kernel<<<dim3(8, 16, 1), 256, 0, stream>>>(
          hid, dwT, down_b + g * H, sel + g * 2048, gates + g * 2048, outf);
    }
  } else {
    u16* upT = (u16*)(ws + base);
    u16* dwT = (u16*)(ws + base + upT_e);
    u16* hid = (u16*)(ws + base + upT_e + dwT_g);
    for (int e = 0; e < 16; ++e) {
      transcvt_kernel<<<dim3(H / 32, DFFT / 32, 1), 256, 0, stream>>>(
          up_w + (size_t)e * H * DFF, upT, H, DFF, H, 0, 0);
      transcvt_kernel<<<dim3(DFFP / 32, H / 32, 1), 256, 0, stream>>>(
          down_w + (size_t)(e >> 2) * DFF * H, dwT, DFF, H, DFFP, 0, 0);
      up_gemm_kernel<<<dim3(22, 4, 1), 256, 0, stream>>>(x, sel, upT, up_b, hid, e);
      down_gemm_kernel<<<dim3(8, 4, 1), 256, 0, stream>>>(
          hid, dwT, down_b + (e >> 2) * H, sel + e * KSEL, gates + e * KSEL, outf);
    }
  }
}

// Round 5
// 637.798 us; speedup vs baseline: 4.6139x; 1.1064x over previous
//
#include <hip/hip_runtime.h>
#include <stdint.h>

#define H 1024
#define NE 16
#define DFF 2730
#define DFFP 2752            // 86*32, zero-padded ffn dim (hid cols / down K)
#define DFFT 2816            // 22*128, padded row count for up_w^T (up N tiles)
#define BS 8192
#define KSEL 512             // tokens per expert (expert choice, c=1)

typedef unsigned short u16;
typedef __attribute__((ext_vector_type(8))) short short8;
typedef __attribute__((ext_vector_type(4))) float f32x4;

__device__ __forceinline__ u16 f2b(float f) {
  unsigned u = __float_as_uint(f);
  unsigned r = (u + 0x7fffu + ((u >> 16) & 1u)) >> 16;
  return (u16)r;
}

// async global->LDS, 16B per lane; LDS dest = wave-uniform base + lane*16
typedef const __attribute__((address_space(1))) unsigned int* gas_t;
typedef __attribute__((address_space(3))) unsigned int* las_t;
__device__ __forceinline__ void gload16(const u16* g, u16* l) {
  __builtin_amdgcn_global_load_lds((gas_t)g, (las_t)l, 16, 0, 0);
}

// ---------------- zero d_out (fp32, poisoned 0xAA before every launch) ----------------
__global__ __launch_bounds__(256) void zero_kernel(f32x4* __restrict__ out) {
  size_t i = ((size_t)blockIdx.x * 256 + threadIdx.x) * 2;
  f32x4 z = {0.f, 0.f, 0.f, 0.f};
  out[i] = z; out[i + 1] = z;
}

// ------- transpose+convert: src fp32 [Ks][Ns] -> dst bf16 [Nd rows][Kd cols] -------
__global__ __launch_bounds__(256) void transcvt_kernel(
    const float* __restrict__ src, u16* __restrict__ dst,
    int Ks, int Ns, int Kd, long src_z, long dst_z) {
  src += (size_t)blockIdx.z * src_z;
  dst += (size_t)blockIdx.z * dst_z;
  __shared__ float t[32][33];
  int k0 = blockIdx.x * 32, n0 = blockIdx.y * 32;
  int r = threadIdx.x >> 3, c4 = (threadIdx.x & 7) * 4;
  int k = k0 + r;
#pragma unroll
  for (int j = 0; j < 4; ++j) {
    int n = n0 + c4 + j;
    t[r][c4 + j] = (k < Ks && n < Ns) ? src[(size_t)k * Ns + n] : 0.f;
  }
  __syncthreads();
  u16 o[4];
#pragma unroll
  for (int j = 0; j < 4; ++j) o[j] = f2b(t[c4 + j][r]);
  *(uint2*)&dst[(size_t)(n0 + r) * Kd + k0 + c4] = *(uint2*)o;
}

// ------- gather+convert: xg[row][:] = bf16(x[sel[row]][:]), one block per row -------
__global__ __launch_bounds__(256) void gather_kernel(
    const float* __restrict__ x, const int* __restrict__ sel, u16* __restrict__ xg) {
  int row = blockIdx.x;
  const float* src = x + (size_t)sel[row] * H + threadIdx.x * 4;
  f32x4 v = *(const f32x4*)src;
  u16 o[4];
#pragma unroll
  for (int j = 0; j < 4; ++j) o[j] = f2b(v[j]);
  *(uint2*)&xg[(size_t)row * H + threadIdx.x * 4] = *(uint2*)o;
}

// ------- router: fp32 in, fp64 logits+softmax -> S64 [NE][BS], S32 [NE][BS] -------
__global__ __launch_bounds__(256) void router_kernel(
    const float* __restrict__ x, const float* __restrict__ rw,
    const float* __restrict__ rb, double* __restrict__ S64, float* __restrict__ S32) {
  int w = threadIdx.x >> 6, lane = threadIdx.x & 63;
  int t = blockIdx.x * 4 + w;
  __shared__ double part[4][64][17];
  double acc[NE];
#pragma unroll
  for (int e = 0; e < NE; ++e) acc[e] = 0.0;
  const float* xr = x + (size_t)t * H + lane * 16;
  f32x4 xv[4];
#pragma unroll
  for (int q = 0; q < 4; ++q) xv[q] = *(const f32x4*)(xr + q * 4);
#pragma unroll
  for (int hh = 0; hh < 16; ++hh) {
    double xf = (double)xv[hh >> 2][hh & 3];
    const float* rwr = rw + (size_t)(lane * 16 + hh) * NE;
    f32x4 wv0 = *(const f32x4*)rwr;
    f32x4 wv1 = *(const f32x4*)(rwr + 4);
    f32x4 wv2 = *(const f32x4*)(rwr + 8);
    f32x4 wv3 = *(const f32x4*)(rwr + 12);
#pragma unroll
    for (int e = 0; e < 4; ++e) acc[e]      += xf * (double)wv0[e];
#pragma unroll
    for (int e = 0; e < 4; ++e) acc[4 + e]  += xf * (double)wv1[e];
#pragma unroll
    for (int e = 0; e < 4; ++e) acc[8 + e]  += xf * (double)wv2[e];
#pragma unroll
    for (int e = 0; e < 4; ++e) acc[12 + e] += xf * (double)wv3[e];
  }
#pragma unroll
  for (int e = 0; e < NE; ++e) part[w][lane][e] = acc[e];
  __syncthreads();
  if (lane < NE) {
    double s = (double)rb[lane];
#pragma unroll 8
    for (int r = 0; r < 64; ++r) s += part[w][r][lane];
    double m = s;
    for (int o = 8; o > 0; o >>= 1) m = fmax(m, __shfl_xor(m, o, 16));
    double ex = exp(s - m);
    double sum = ex;
    for (int o = 8; o > 0; o >>= 1) sum += __shfl_xor(sum, o, 16);
    double Sv = ex / sum;
    S64[(size_t)lane * BS + t] = Sv;
    S32[(size_t)lane * BS + t] = (float)Sv;
  }
}

// ---------------- exact top-k (k=512) per expert, fp64 tie-refinement ----------------
__global__ __launch_bounds__(256) void topk_kernel(
    const float* __restrict__ S32, const double* __restrict__ S64,
    int* __restrict__ sel, float* __restrict__ gates) {
  int e = blockIdx.x, tid = threadIdx.x;
  __shared__ float sv[BS];
  __shared__ int red[4];
  __shared__ int cnt_s, gt_s, tie_cnt;
  __shared__ int tie_idx[256];
  const float* row = S32 + (size_t)e * BS;
  for (int i = tid; i < BS; i += 256) sv[i] = row[i];
  if (tid == 0) tie_cnt = 0;
  __syncthreads();
  unsigned thr = 0;
  for (int bit = 31; bit >= 0; --bit) {
    unsigned cand = thr | (1u << bit);
    int c = 0;
    for (int i = tid; i < BS; i += 256) c += (__float_as_uint(sv[i]) >= cand) ? 1 : 0;
#pragma unroll
    for (int o = 32; o > 0; o >>= 1) c += __shfl_down(c, o);
    if ((tid & 63) == 0) red[tid >> 6] = c;
    __syncthreads();
    if (tid == 0) cnt_s = red[0] + red[1] + red[2] + red[3];
    __syncthreads();
    if (cnt_s >= KSEL) thr = cand;
    __syncthreads();
  }
  {
    int c = 0;
    for (int i = tid; i < BS; i += 256) c += (__float_as_uint(sv[i]) > thr) ? 1 : 0;
#pragma unroll
    for (int o = 32; o > 0; o >>= 1) c += __shfl_down(c, o);
    if ((tid & 63) == 0) red[tid >> 6] = c;
    __syncthreads();
    if (tid == 0) gt_s = red[0] + red[1] + red[2] + red[3];
    __syncthreads();
  }
  int gt = gt_s;
  if (tid < 64) {
    int lane = tid, pos = 0;
    for (int c = 0; c < BS / 64; ++c) {
      int i = c * 64 + lane;
      bool p = __float_as_uint(sv[i]) > thr;
      unsigned long long b = __ballot(p);
      int rank = __popcll(b & ((1ull << lane) - 1ull));
      if (p) { sel[e * KSEL + pos + rank] = i; gates[e * KSEL + pos + rank] = sv[i]; }
      pos += __popcll(b);
    }
  }
  for (int i = tid; i < BS; i += 256) {
    if (__float_as_uint(sv[i]) == thr) {
      int p = atomicAdd(&tie_cnt, 1);
      if (p < 256) tie_idx[p] = i;
    }
  }
  __syncthreads();
  int T = tie_cnt < 256 ? tie_cnt : 256;
  int R = KSEL - gt;
  if (tid < T) {
    int i = tie_idx[tid];
    double vi = S64[(size_t)e * BS + i];
    int rank = 0;
    for (int j = 0; j < T; ++j) {
      if (j == tid) continue;
      int kdx = tie_idx[j];
      double vj = S64[(size_t)e * BS + kdx];
      rank += (vj > vi || (vj == vi && kdx < i)) ? 1 : 0;
    }
    if (rank < R) {
      sel[e * KSEL + gt + rank] = i;
      gates[e * KSEL + gt + rank] = sv[i];
    }
  }
}

// ======================= m97-style GEMM kernels ============================
// LDS tile: 128 rows x 32 u16, row-major, XOR-swizzled 16B blocks:
//   block(r, b) holds global k-block  b ^ ((r>>1)&3)   (b = 0..3, 8 u16 each)
// -> ds_read_b128 fragment reads are <=2-way bank aliased (free), and
//    global_load_lds staging is contiguous in lane order (wave-uniform base).

// ------- up GEMM: hid[z][m][n] = silu(xg[z] @ upT[z]^T + up_b[e]) -------
__global__ __launch_bounds__(256) void up_gemm_kernel(
    const u16* __restrict__ xg, const u16* __restrict__ upT,
    const float* __restrict__ up_b, u16* __restrict__ hid, int e_base) {
  int mt = blockIdx.x;            // 0..3  (fastest: consecutive blocks share B stripe)
  int nt = blockIdx.y;            // 0..21
  int z = blockIdx.z;
  int e = e_base + z;
  const u16* Abase = xg + (size_t)z * KSEL * H + (size_t)(mt * 128) * H;
  const u16* Bbase = upT + (size_t)z * DFFT * H + (size_t)(nt * 128) * H;
  u16* hidz = hid + (size_t)z * KSEL * DFFP;
  int tid = threadIdx.x, lane = tid & 63, w = tid >> 6;
  int wm = (w >> 1) * 64, wn = (w & 1) * 64;
  int n0 = nt * 128, m0 = mt * 128;
  __shared__ __align__(16) u16 As[128 * 32];
  __shared__ __align__(16) u16 Bs[128 * 32];
  // staging source addresses (two 16B issues per thread per tile)
  int r0 = tid >> 2, cg0 = (tid & 3) ^ ((r0 >> 1) & 3);
  const u16* pa0 = Abase + (size_t)r0 * H + cg0 * 8;
  const u16* pa1 = Abase + (size_t)(r0 + 64) * H + cg0 * 8;   // same cg (r+64 keeps (r>>1)&3)
  const u16* pb0 = Bbase + (size_t)r0 * H + cg0 * 8;
  const u16* pb1 = Bbase + (size_t)(r0 + 64) * H + cg0 * 8;
  u16* la0 = As + tid * 8;  u16* la1 = As + 2048 + tid * 8;
  u16* lb0 = Bs + tid * 8;  u16* lb1 = Bs + 2048 + tid * 8;
  f32x4 zero = {0.f, 0.f, 0.f, 0.f};
  f32x4 acc[4][4];
#pragma unroll
  for (int i = 0; i < 4; ++i)
#pragma unroll
    for (int j = 0; j < 4; ++j) acc[i][j] = zero;
  int lm = lane & 15, g = lane >> 4;
  for (int k0 = 0; k0 < H; k0 += 32) {
    gload16(pa0 + k0, la0);
    gload16(pa1 + k0, la1);
    gload16(pb0 + k0, lb0);
    gload16(pb1 + k0, lb1);
    __syncthreads();                 // drains vmcnt -> LDS tiles ready
    short8 af[4], bfr[4];
#pragma unroll
    for (int i = 0; i < 4; ++i) {
      int row = wm + i * 16 + lm;
      af[i] = *(short8*)&As[row * 32 + ((g ^ ((row >> 1) & 3)) * 8)];
    }
#pragma unroll
    for (int j = 0; j < 4; ++j) {
      int row = wn + j * 16 + lm;
      bfr[j] = *(short8*)&Bs[row * 32 + ((g ^ ((row >> 1) & 3)) * 8)];
    }
#pragma unroll
    for (int i = 0; i < 4; ++i)
#pragma unroll
      for (int j = 0; j < 4; ++j)
        acc[i][j] = __builtin_amdgcn_mfma_f32_16x16x32_bf16(af[i], bfr[j], acc[i][j], 0, 0, 0);
    __syncthreads();                 // all reads done before next overwrite
  }
  int q = lane >> 4;
#pragma unroll
  for (int i = 0; i < 4; ++i) {
#pragma unroll
    for (int j = 0; j < 4; ++j) {
      int col = n0 + wn + j * 16 + lm;
      if (col >= DFFP) continue;
      float bias = (col < DFF) ? up_b[(size_t)e * DFF + col] : 0.f;
#pragma unroll
      for (int r = 0; r < 4; ++r) {
        int rowl = m0 + wm + i * 16 + q * 4 + r;
        float v = acc[i][j][r] + bias;
        v = v / (1.f + __expf(-v));           // silu
        hidz[(size_t)rowl * DFFP + col] = f2b(v);
      }
    }
  }
}

// ------- down GEMM (z = group, merged M=2048) + gated fp32 atomicAdd scatter -------
__global__ __launch_bounds__(256) void down_gemm_kernel(
    const u16* __restrict__ hid, const u16* __restrict__ dwT,
    const float* __restrict__ db, const int* __restrict__ selp,
    const float* __restrict__ gatesp, float* __restrict__ out) {
  int mt = blockIdx.x;            // 0..15 (fastest)
  int nt = blockIdx.y;            // 0..7
  int z = blockIdx.z;             // group
  const u16* Abase = hid + (size_t)z * 2048 * DFFP + (size_t)(mt * 128) * DFFP;
  const u16* Bbase = dwT + (size_t)z * H * DFFP + (size_t)(nt * 128) * DFFP;
  const float* dbz = db + (size_t)z * H;
  int tid = threadIdx.x, lane = tid & 63, w = tid >> 6;
  int wm = (w >> 1) * 64, wn = (w & 1) * 64;
  int n0 = nt * 128, m0 = mt * 128;
  __shared__ __align__(16) u16 As[128 * 32];
  __shared__ __align__(16) u16 Bs[128 * 32];
  __shared__ int sel_s[128];
  __shared__ float gate_s[128];
  if (tid < 128) {
    sel_s[tid] = selp[z * 2048 + m0 + tid];
    gate_s[tid] = gatesp[z * 2048 + m0 + tid];
  }
  int r0 = tid >> 2, cg0 = (tid & 3) ^ ((r0 >> 1) & 3);
  const u16* pa0 = Abase + (size_t)r0 * DFFP + cg0 * 8;
  const u16* pa1 = Abase + (size_t)(r0 + 64) * DFFP + cg0 * 8;
  const u16* pb0 = Bbase + (size_t)r0 * DFFP + cg0 * 8;
  const u16* pb1 = Bbase + (size_t)(r0 + 64) * DFFP + cg0 * 8;
  u16* la0 = As + tid * 8;  u16* la1 = As + 2048 + tid * 8;
  u16* lb0 = Bs + tid * 8;  u16* lb1 = Bs + 2048 + tid * 8;
  f32x4 zero = {0.f, 0.f, 0.f, 0.f};
  f32x4 acc[4][4];
#pragma unroll
  for (int i = 0; i < 4; ++i)
#pragma unroll
    for (int j = 0; j < 4; ++j) acc[i][j] = zero;
  int lm = lane & 15, g = lane >> 4;
  __syncthreads();                   // sel_s/gate_s visible (also before first stage)
  for (int k0 = 0; k0 < DFFP; k0 += 32) {
    gload16(pa0 + k0, la0);
    gload16(pa1 + k0, la1);
    gload16(pb0 + k0, lb0);
    gload16(pb1 + k0, lb1);
    __syncthreads();
    short8 af[4], bfr[4];
#pragma unroll
    for (int i = 0; i < 4; ++i) {
      int row = wm + i * 16 + lm;
      af[i] = *(short8*)&As[row * 32 + ((g ^ ((row >> 1) & 3)) * 8)];
    }
#pragma unroll
    for (int j = 0; j < 4; ++j) {
      int row = wn + j * 16 + lm;
      bfr[j] = *(short8*)&Bs[row * 32 + ((g ^ ((row >> 1) & 3)) * 8)];
    }
#pragma unroll
    for (int i = 0; i < 4; ++i)
#pragma unroll
      for (int j = 0; j < 4; ++j)
        acc[i][j] = __builtin_amdgcn_mfma_f32_16x16x32_bf16(af[i], bfr[j], acc[i][j], 0, 0, 0);
    __syncthreads();
  }
  int q = lane >> 4;
#pragma unroll
  for (int i = 0; i < 4; ++i) {
#pragma unroll
    for (int j = 0; j < 4; ++j) {
      int col = n0 + wn + j * 16 + lm;
      float bias = dbz[col];
#pragma unroll
      for (int r = 0; r < 4; ++r) {
        int rowl = wm + i * 16 + q * 4 + r;
        float v = (acc[i][j][r] + bias) * gate_s[rowl];
        atomicAdd(&out[(size_t)sel_s[rowl] * H + col], v);
      }
    }
  }
}

extern "C" void kernel_launch(void* const* d_in, const int* in_sizes, int n_in,
                              void* d_out, int out_size, void* d_ws, size_t ws_size,
                              hipStream_t stream) {
  const float* x      = (const float*)d_in[0];
  const float* rw     = (const float*)d_in[1];
  const float* rb     = (const float*)d_in[2];
  const float* up_w   = (const float*)d_in[3];
  const float* up_b   = (const float*)d_in[4];
  const float* down_w = (const float*)d_in[5];
  const float* down_b = (const float*)d_in[6];
  char* ws = (char*)d_ws;
  double* S64  = (double*)ws;                  // 1,048,576 B
  float*  S32  = (float*)(ws + 1048576);       //   524,288 B
  int*    sel  = (int*)(ws + 1572864);         //    32,768 B
  float*  gates= (float*)(ws + 1605632);       //    32,768 B
  const size_t base = 1638400;

  const size_t upT_e  = (size_t)DFFT * H * 2;     // 5,767,168 B per expert
  const size_t dwT_g  = (size_t)H * DFFP * 2;     // 5,636,096 B per group
  const size_t hid_e  = (size_t)KSEL * DFFP * 2;  // 2,818,048 B per expert
  const size_t xg_e   = (size_t)KSEL * H * 2;     // 1,048,576 B per expert

  size_t need16 = base + 16 * upT_e + 4 * dwT_g + 16 * hid_e + 16 * xg_e;  // ~180 MB
  size_t need4  = base + 4 * upT_e + 1 * dwT_g + 4 * hid_e + 4 * xg_e;     // ~45.8 MB
  int cs = (ws_size >= need16) ? 16 : (ws_size >= need4 ? 4 : 1);

  float* outf = (float*)d_out;
  zero_kernel<<<BS * H / 8 / 256, 256, 0, stream>>>((f32x4*)d_out);
  router_kernel<<<BS / 4, 256, 0, stream>>>(x, rw, rb, S64, S32);
  topk_kernel<<<NE, 256, 0, stream>>>(S32, S64, sel, gates);

  if (cs == 16) {
    u16* upT = (u16*)(ws + base);
    u16* dwT = (u16*)(ws + base + 16 * upT_e);
    u16* hid = (u16*)(ws + base + 16 * upT_e + 4 * dwT_g);
    u16* xg  = (u16*)(ws + base + 16 * upT_e + 4 * dwT_g + 16 * hid_e);
    transcvt_kernel<<<dim3(H / 32, DFFT / 32, 16), 256, 0, stream>>>(
        up_w, upT, H, DFF, H, (long)H * DFF, (long)DFFT * H);
    transcvt_kernel<<<dim3(DFFP / 32, H / 32, 4), 256, 0, stream>>>(
        down_w, dwT, DFF, H, DFFP, (long)DFF * H, (long)H * DFFP);
    gather_kernel<<<NE * KSEL, 256, 0, stream>>>(x, sel, xg);
    up_gemm_kernel<<<dim3(4, 22, 16), 256, 0, stream>>>(xg, upT, up_b, hid, 0);
    down_gemm_kernel<<<dim3(16, 8, 4), 256, 0, stream>>>(hid, dwT, down_b, sel, gates, outf);
  } else if (cs == 4) {
    u16* upT = (u16*)(ws + base);
    u16* dwT = (u16*)(ws + base + 4 * upT_e);
    u16* hid = (u16*)(ws + base + 4 * upT_e + dwT_g);
    u16* xg  = (u16*)(ws + base + 4 * upT_e + dwT_g + 4 * hid_e);
    for (int g = 0; g < 4; ++g) {
      transcvt_kernel<<<dim3(H / 32, DFFT / 32, 4), 256, 0, stream>>>(
          up_w + (size_t)g * 4 * H * DFF, upT, H, DFF, H, (long)H * DFF, (long)DFFT * H);
      transcvt_kernel<<<dim3(DFFP / 32, H / 32, 1), 256, 0, stream>>>(
          down_w + (size_t)g * DFF * H, dwT, DFF, H, DFFP, 0, 0);
      gather_kernel<<<4 * KSEL, 256, 0, stream>>>(x, sel + g * 2048, xg);
      up_gemm_kernel<<<dim3(4, 22, 4), 256, 0, stream>>>(xg, upT, up_b, hid, g * 4);
      down_gemm_kernel<<<dim3(16, 8, 1), 256, 0, stream>>>(
          hid, dwT, down_b + g * H, sel + g * 2048, gates + g * 2048, outf);
    }
  } else {
    u16* upT = (u16*)(ws + base);
    u16* dwT = (u16*)(ws + base + upT_e);
    u16* hid = (u16*)(ws + base + upT_e + dwT_g);
    u16* xg  = (u16*)(ws + base + upT_e + dwT_g + hid_e);
    for (int e = 0; e < 16; ++e) {
      transcvt_kernel<<<dim3(H / 32, DFFT / 32, 1), 256, 0, stream>>>(
          up_w + (size_t)e * H * DFF, upT, H, DFF, H, 0, 0);
      transcvt_kernel<<<dim3(DFFP / 32, H / 32, 1), 256, 0, stream>>>(
          down_w + (size_t)(e >> 2) * DFF * H, dwT, DFF, H, DFFP, 0, 0);
      gather_kernel<<<KSEL, 256, 0, stream>>>(x, sel + e * KSEL, xg);
      up_gemm_kernel<<<dim3(4, 22, 1), 256, 0, stream>>>(xg, upT, up_b, hid, e);
      // per-expert: M=512 -> 4 m-tiles
      down_gemm_kernel<<<dim3(4, 8, 1), 256, 0, stream>>>(
          hid, dwT, down_b + (e >> 2) * H, sel + e * KSEL, gates + e * KSEL, outf);
    }
  }
}